// Round 8
// baseline (107.120 us; speedup 1.0000x reference)
//
#include <hip/hip_runtime.h>

#define NBATCH 8192
#define NELEC  16
#define NMO    32
#define NCONF  64
#define NS     8          // NUP == NDOWN == 8
#define TSTR   20         // transposed row stride in floats (80 B: 16B-aligned)
#define TSZ    (NMO * TSTR)

typedef float v2f __attribute__((ext_vector_type(2)));

__device__ __forceinline__ v2f pkfma(v2f a, v2f b, v2f c) {
#if __has_builtin(__builtin_elementwise_fma)
    return __builtin_elementwise_fma(a, b, c);
#else
    return a * b + c;
#endif
}
__device__ __forceinline__ v2f bc2(float s) { return (v2f){s, s}; }
__device__ __forceinline__ float getel2(const v2f (&R)[4], int j) {
    return (j & 1) ? R[j >> 1].y : R[j >> 1].x;
}
__device__ __forceinline__ void setel2(v2f (&R)[4], int j, float v) {
    if (j & 1) R[j >> 1].y = v; else R[j >> 1].x = v;
}

// One spin channel. A' (transposed fragment) comes from LDS (MO^T staging,
// 2x ds_read_b128 per row). D' rows now come STRAIGHT FROM GLOBAL (L1):
// D'[k][i] = d2MO[b][eoff+i][cols[k]] — stride-128B scalar loads. Each d2MO
// row is exactly one 128B cache line, so for fixed i all lanes hit the same
// L1 line -> TCP same-line merging; this rides the TA/vector pipe, which is
// idle, while A rides the DS pipe (R7 analysis: DS pipe w/ random-gather
// conflicts is the bottleneck; splitting halves DS traffic).
// R3/R4 lesson: rows of D' pair with columns of A'^-1 — keep this pairing.
__device__ __forceinline__ void solve8T(const float* __restrict__ MOT,
                                        const float* __restrict__ d2sp,  // global, pre-offset to spin block
                                        const int (&cols)[NS], int eoff,
                                        float& det_out, float& tr_out)
{
    v2f A2[NS][4];                    // row j, pair p = cols {2p, 2p+1}
    #pragma unroll
    for (int j = 0; j < NS; ++j) {
        const float4* pa = (const float4*)(MOT + cols[j] * TSTR + eoff);
        float4 a0 = pa[0], a1 = pa[1];
        A2[j][0] = (v2f){a0.x, a0.y};
        A2[j][1] = (v2f){a0.z, a0.w};
        A2[j][2] = (v2f){a1.x, a1.y};
        A2[j][3] = (v2f){a1.z, a1.w};
    }

    // In-place LU, no pivot (R2-proven numerics; packed over column pairs, R7).
    float det = 1.0f;
    #pragma unroll
    for (int k = 0; k < NS; ++k) {
        float ukk = getel2(A2[k], k);
        det *= ukk;
        float pinv = __builtin_amdgcn_rcpf(ukk);
        #pragma unroll
        for (int r = k + 1; r < NS; ++r) {
            float m = getel2(A2[r], k) * pinv;
            v2f m2 = bc2(m);
            #pragma unroll
            for (int p = (k + 1) >> 1; p < 4; ++p)
                A2[r][p] = pkfma(-m2, A2[k][p], A2[r][p]);
            setel2(A2[r], k, m);
        }
        setel2(A2[k], k, pinv);
    }

    // tr = sum_k <x(k), row_k(D')> with A' x(k) = e_k; k pairs in lo/hi halves.
    float tr = 0.0f;
    #pragma unroll
    for (int t = 0; t < 4; ++t) {
        const int k0 = 2 * t, k1 = 2 * t + 1;

        // D' rows k0,k1 from global: one address reg per column + imm offsets
        const float* c0p = d2sp + cols[k0];
        const float* c1p = d2sp + cols[k1];
        float dk0[NS], dk1[NS];
        #pragma unroll
        for (int i = 0; i < NS; ++i) {
            dk0[i] = c0p[i * NMO];
            dk1[i] = c1p[i * NMO];
        }

        // forward: y2[i] = { y_{k0}[i], y_{k1}[i] }, y = L^-1 e_k
        v2f y2[NS];
        y2[k0] = (v2f){1.0f, 0.0f};
        y2[k1] = (v2f){-getel2(A2[k1], k0), 1.0f};
        #pragma unroll
        for (int i = k1 + 1; i < NS; ++i) {
            v2f acc = (v2f){0.0f, 0.0f};
            #pragma unroll
            for (int j = k0; j < i; ++j)
                acc = pkfma(bc2(getel2(A2[i], j)), y2[j], acc);
            y2[i] = -acc;
        }

        // back: U x = y
        v2f x2[NS];
        #pragma unroll
        for (int i = NS - 1; i >= 0; --i) {
            v2f acc = (i >= k0) ? y2[i] : (v2f){0.0f, 0.0f};
            #pragma unroll
            for (int c2 = i + 1; c2 < NS; ++c2)
                acc = pkfma(-bc2(getel2(A2[i], c2)), x2[c2], acc);
            x2[i] = acc * bc2(getel2(A2[i], i));
        }

        #pragma unroll
        for (int i = 0; i < NS; ++i) {
            tr = fmaf(x2[i].x, dk0[i], tr);
            tr = fmaf(x2[i].y, dk1[i], tr);
        }
    }

    det_out = det;
    tr_out  = tr;
}

// 2 threads per (batch, config) pair: lane parity = spin; combine via shfl_xor.
__global__ __launch_bounds__(256)
void kp_l1d_kernel(const float* __restrict__ MO,
                   const float* __restrict__ d2MO,
                   const int*   __restrict__ cfg_up,
                   const int*   __restrict__ cfg_dn,
                   float*       __restrict__ out)
{
    __shared__ float smem[2][TSZ];           // [batch-half][MO^T only] — D no longer staged

    const int tid  = threadIdx.x;
    const int half = tid >> 7;               // batch within block (0/1)
    const int u    = tid & 127;              // id within the batch's 128 threads
    const int b    = blockIdx.x * 2 + half;  // batch index

    float* MOT = smem[half];

    const float* MOb = MO   + (size_t)b * NELEC * NMO;
    const float* d2b = d2MO + (size_t)b * NELEC * NMO;

    // Stage MO^T (512 floats) with 128 threads: one float4 per thread, coalesced.
    {
        int r = u >> 3;
        int c = (u & 7) * 4;
        float4 v = *(const float4*)(MOb + r * NMO + c);
        MOT[(c + 0) * TSTR + r] = v.x;
        MOT[(c + 1) * TSTR + r] = v.y;
        MOT[(c + 2) * TSTR + r] = v.z;
        MOT[(c + 3) * TSTR + r] = v.w;
    }
    __syncthreads();

    const int cidx = u >> 1;                 // config index 0..63
    const int s    = u & 1;                  // 0 = up, 1 = down
    const int* cfg = s ? cfg_dn : cfg_up;
    int4 c0 = ((const int4*)cfg)[cidx * 2 + 0];
    int4 c1 = ((const int4*)cfg)[cidx * 2 + 1];
    const int cols[NS] = {c0.x, c0.y, c0.z, c0.w, c1.x, c1.y, c1.z, c1.w};

    float det, tr;
    solve8T(MOT, d2b + s * NS * NMO, cols, s * NS, det, tr);

    // partner lane (u^1, same wave) holds the other spin channel
    float det_o = __shfl_xor(det, 1);
    float tr_o  = __shfl_xor(tr, 1);
    if (s == 0)
        out[(size_t)b * NCONF + cidx] = -0.5f * (tr + tr_o) * det * det_o;
}

extern "C" void kernel_launch(void* const* d_in, const int* in_sizes, int n_in,
                              void* d_out, int out_size, void* d_ws, size_t ws_size,
                              hipStream_t stream)
{
    const float* MO     = (const float*)d_in[0];
    const float* d2MO   = (const float*)d_in[1];
    const int*   cfg_up = (const int*)d_in[2];
    const int*   cfg_dn = (const int*)d_in[3];
    float* out = (float*)d_out;

    dim3 grid(NBATCH / 2);   // 4096 blocks, 2 batches per block, 2 threads per pair
    dim3 block(256);
    kp_l1d_kernel<<<grid, block, 0, stream>>>(MO, d2MO, cfg_up, cfg_dn, out);
}

// Round 9
// 93.236 us; speedup vs baseline: 1.1489x; 1.1489x over previous
//
#include <hip/hip_runtime.h>

#define NBATCH 8192
#define NELEC  16
#define NMO    32
#define NCONF  64
#define NS     8          // NUP == NDOWN == 8
#define TSTR   20         // transposed row stride in floats (80 B: 16B-aligned for b128)
#define TSZ    (NMO * TSTR)

typedef float v2f __attribute__((ext_vector_type(2)));

__device__ __forceinline__ v2f pkfma(v2f a, v2f b, v2f c) {
#if __has_builtin(__builtin_elementwise_fma)
    return __builtin_elementwise_fma(a, b, c);
#else
    return a * b + c;
#endif
}
__device__ __forceinline__ v2f bc2(float s) { return (v2f){s, s}; }
__device__ __forceinline__ float getel2(const v2f (&R)[4], int j) {
    return (j & 1) ? R[j >> 1].y : R[j >> 1].x;
}
__device__ __forceinline__ void setel2(v2f (&R)[4], int j, float v) {
    if (j & 1) R[j >> 1].y = v; else R[j >> 1].x = v;
}

// R7-proven solve: A' and D' rows both from LDS (R8 showed the global-D path
// regresses: 64 scalar L2-latency loads/thread at ~10 resident waves/CU is
// fully exposed latency; LDS conflicts measured at only ~7% — not the issue).
// R3/R4 lesson: rows of D' pair with columns of A'^-1; keep this pairing.
__device__ __forceinline__ void solve8T(const float* __restrict__ MOT,
                                        const float* __restrict__ D2T,
                                        const int (&cols)[NS], int eoff,
                                        float& det_out, float& tr_out)
{
    v2f A2[NS][4];                    // row j, pair p = cols {2p, 2p+1}
    #pragma unroll
    for (int j = 0; j < NS; ++j) {
        const float4* pa = (const float4*)(MOT + cols[j] * TSTR + eoff);
        float4 a0 = pa[0], a1 = pa[1];
        A2[j][0] = (v2f){a0.x, a0.y};
        A2[j][1] = (v2f){a0.z, a0.w};
        A2[j][2] = (v2f){a1.x, a1.y};
        A2[j][3] = (v2f){a1.z, a1.w};
    }

    // In-place LU, no pivot (R2-proven numerics; packed over column pairs).
    float det = 1.0f;
    #pragma unroll
    for (int k = 0; k < NS; ++k) {
        float ukk = getel2(A2[k], k);
        det *= ukk;
        float pinv = __builtin_amdgcn_rcpf(ukk);
        #pragma unroll
        for (int r = k + 1; r < NS; ++r) {
            float m = getel2(A2[r], k) * pinv;
            v2f m2 = bc2(m);
            #pragma unroll
            for (int p = (k + 1) >> 1; p < 4; ++p)
                A2[r][p] = pkfma(-m2, A2[k][p], A2[r][p]);
            setel2(A2[r], k, m);
        }
        setel2(A2[k], k, pinv);
    }

    // tr = sum_k <x(k), row_k(D')> with A' x(k) = e_k; k pairs in lo/hi halves.
    float tr = 0.0f;
    #pragma unroll
    for (int t = 0; t < 4; ++t) {
        const int k0 = 2 * t, k1 = 2 * t + 1;

        const float4* pd0 = (const float4*)(D2T + cols[k0] * TSTR + eoff);
        const float4* pd1 = (const float4*)(D2T + cols[k1] * TSTR + eoff);
        float4 d00 = pd0[0], d01 = pd0[1];
        float4 d10 = pd1[0], d11 = pd1[1];
        const float dk0[NS] = {d00.x, d00.y, d00.z, d00.w, d01.x, d01.y, d01.z, d01.w};
        const float dk1[NS] = {d10.x, d10.y, d10.z, d10.w, d11.x, d11.y, d11.z, d11.w};

        // forward: y2[i] = { y_{k0}[i], y_{k1}[i] }, y = L^-1 e_k
        v2f y2[NS];
        y2[k0] = (v2f){1.0f, 0.0f};
        y2[k1] = (v2f){-getel2(A2[k1], k0), 1.0f};
        #pragma unroll
        for (int i = k1 + 1; i < NS; ++i) {
            v2f acc = (v2f){0.0f, 0.0f};
            #pragma unroll
            for (int j = k0; j < i; ++j)
                acc = pkfma(bc2(getel2(A2[i], j)), y2[j], acc);
            y2[i] = -acc;
        }

        // back: U x = y
        v2f x2[NS];
        #pragma unroll
        for (int i = NS - 1; i >= 0; --i) {
            v2f acc = (i >= k0) ? y2[i] : (v2f){0.0f, 0.0f};
            #pragma unroll
            for (int c2 = i + 1; c2 < NS; ++c2)
                acc = pkfma(-bc2(getel2(A2[i], c2)), x2[c2], acc);
            x2[i] = acc * bc2(getel2(A2[i], i));
        }

        #pragma unroll
        for (int i = 0; i < NS; ++i) {
            tr = fmaf(x2[i].x, dk0[i], tr);
            tr = fmaf(x2[i].y, dk1[i], tr);
        }
    }

    det_out = det;
    tr_out  = tr;
}

// R9: 512-thread blocks (4 batches/block) — tests the residency hypothesis:
// measured occupancy is ~2.5 blocks/CU regardless of VGPR/LDS headroom, so
// packing 2x waves per block should ~2x resident waves. Per-thread work is
// bit-identical to R7 (2 threads per pair, lane parity = spin).
__global__ __launch_bounds__(512)
void kp_b512_kernel(const float* __restrict__ MO,
                    const float* __restrict__ d2MO,
                    const int*   __restrict__ cfg_up,
                    const int*   __restrict__ cfg_dn,
                    float*       __restrict__ out)
{
    __shared__ float smem[4][2][TSZ];        // [batch-quarter][MO^T / d2MO^T][32 x 20]

    const int tid  = threadIdx.x;
    const int q    = tid >> 7;               // batch within block (0..3)
    const int u    = tid & 127;              // id within the batch's 128 threads
    const int b    = blockIdx.x * 4 + q;     // batch index

    float* MOT = smem[q][0];
    float* D2T = smem[q][1];

    const float* MOb = MO   + (size_t)b * NELEC * NMO;
    const float* d2b = d2MO + (size_t)b * NELEC * NMO;

    // Stage MO^T and d2MO^T (512 floats each) with 128 threads: one float4 per
    // array per thread, fully coalesced. r = u/8 in 0..15, c = (u%8)*4.
    {
        int r = u >> 3;
        int c = (u & 7) * 4;
        float4 v = *(const float4*)(MOb + r * NMO + c);
        float4 w = *(const float4*)(d2b + r * NMO + c);
        MOT[(c + 0) * TSTR + r] = v.x;
        MOT[(c + 1) * TSTR + r] = v.y;
        MOT[(c + 2) * TSTR + r] = v.z;
        MOT[(c + 3) * TSTR + r] = v.w;
        D2T[(c + 0) * TSTR + r] = w.x;
        D2T[(c + 1) * TSTR + r] = w.y;
        D2T[(c + 2) * TSTR + r] = w.z;
        D2T[(c + 3) * TSTR + r] = w.w;
    }
    __syncthreads();

    const int cidx = u >> 1;                 // config index 0..63
    const int s    = u & 1;                  // 0 = up, 1 = down
    const int* cfg = s ? cfg_dn : cfg_up;
    int4 c0 = ((const int4*)cfg)[cidx * 2 + 0];
    int4 c1 = ((const int4*)cfg)[cidx * 2 + 1];
    const int cols[NS] = {c0.x, c0.y, c0.z, c0.w, c1.x, c1.y, c1.z, c1.w};

    float det, tr;
    solve8T(MOT, D2T, cols, s * NS, det, tr);

    // partner lane (u^1, same wave) holds the other spin channel
    float det_o = __shfl_xor(det, 1);
    float tr_o  = __shfl_xor(tr, 1);
    if (s == 0)
        out[(size_t)b * NCONF + cidx] = -0.5f * (tr + tr_o) * det * det_o;
}

extern "C" void kernel_launch(void* const* d_in, const int* in_sizes, int n_in,
                              void* d_out, int out_size, void* d_ws, size_t ws_size,
                              hipStream_t stream)
{
    const float* MO     = (const float*)d_in[0];
    const float* d2MO   = (const float*)d_in[1];
    const int*   cfg_up = (const int*)d_in[2];
    const int*   cfg_dn = (const int*)d_in[3];
    float* out = (float*)d_out;

    dim3 grid(NBATCH / 4);   // 2048 blocks, 4 batches (wave-pairs) per block
    dim3 block(512);
    kp_b512_kernel<<<grid, block, 0, stream>>>(MO, d2MO, cfg_up, cfg_dn, out);
}

// Round 10
// 92.982 us; speedup vs baseline: 1.1521x; 1.0027x over previous
//
#include <hip/hip_runtime.h>

#define NBATCH 8192
#define NELEC  16
#define NMO    32
#define NCONF  64
#define NS     8          // NUP == NDOWN == 8
#define TSTR   20         // transposed row stride in floats (80 B: 16B-aligned for b128)
#define TSZ    (NMO * TSTR)
#define NBPB   4          // batches per block (grid-stride)
#define GRIDN  (NBATCH / NBPB)   // 2048 blocks

typedef float v2f __attribute__((ext_vector_type(2)));

__device__ __forceinline__ v2f pkfma(v2f a, v2f b, v2f c) {
#if __has_builtin(__builtin_elementwise_fma)
    return __builtin_elementwise_fma(a, b, c);
#else
    return a * b + c;
#endif
}
__device__ __forceinline__ v2f bc2(float s) { return (v2f){s, s}; }
__device__ __forceinline__ float getel2(const v2f (&R)[4], int j) {
    return (j & 1) ? R[j >> 1].y : R[j >> 1].x;
}
__device__ __forceinline__ void setel2(v2f (&R)[4], int j, float v) {
    if (j & 1) R[j >> 1].y = v; else R[j >> 1].x = v;
}

// R7-proven solve (byte-identical): A' and D' rows from LDS; in-place no-pivot
// LU packed over column pairs; tr = sum_k <col_k(A'^-1), row_k(D')> with the
// 8 unit-RHS solves packed over k pairs. R3/R4 lesson: rows of D' pair with
// columns of A'^-1 — keep this pairing. R8 lesson: D' from global regresses
// (exposed L2 latency at low residency).
__device__ __forceinline__ void solve8T(const float* __restrict__ MOT,
                                        const float* __restrict__ D2T,
                                        const int (&cols)[NS], int eoff,
                                        float& det_out, float& tr_out)
{
    v2f A2[NS][4];                    // row j, pair p = cols {2p, 2p+1}
    #pragma unroll
    for (int j = 0; j < NS; ++j) {
        const float4* pa = (const float4*)(MOT + cols[j] * TSTR + eoff);
        float4 a0 = pa[0], a1 = pa[1];
        A2[j][0] = (v2f){a0.x, a0.y};
        A2[j][1] = (v2f){a0.z, a0.w};
        A2[j][2] = (v2f){a1.x, a1.y};
        A2[j][3] = (v2f){a1.z, a1.w};
    }

    float det = 1.0f;
    #pragma unroll
    for (int k = 0; k < NS; ++k) {
        float ukk = getel2(A2[k], k);
        det *= ukk;
        float pinv = __builtin_amdgcn_rcpf(ukk);
        #pragma unroll
        for (int r = k + 1; r < NS; ++r) {
            float m = getel2(A2[r], k) * pinv;
            v2f m2 = bc2(m);
            #pragma unroll
            for (int p = (k + 1) >> 1; p < 4; ++p)
                A2[r][p] = pkfma(-m2, A2[k][p], A2[r][p]);
            setel2(A2[r], k, m);
        }
        setel2(A2[k], k, pinv);
    }

    float tr = 0.0f;
    #pragma unroll
    for (int t = 0; t < 4; ++t) {
        const int k0 = 2 * t, k1 = 2 * t + 1;

        const float4* pd0 = (const float4*)(D2T + cols[k0] * TSTR + eoff);
        const float4* pd1 = (const float4*)(D2T + cols[k1] * TSTR + eoff);
        float4 d00 = pd0[0], d01 = pd0[1];
        float4 d10 = pd1[0], d11 = pd1[1];
        const float dk0[NS] = {d00.x, d00.y, d00.z, d00.w, d01.x, d01.y, d01.z, d01.w};
        const float dk1[NS] = {d10.x, d10.y, d10.z, d10.w, d11.x, d11.y, d11.z, d11.w};

        v2f y2[NS];
        y2[k0] = (v2f){1.0f, 0.0f};
        y2[k1] = (v2f){-getel2(A2[k1], k0), 1.0f};
        #pragma unroll
        for (int i = k1 + 1; i < NS; ++i) {
            v2f acc = (v2f){0.0f, 0.0f};
            #pragma unroll
            for (int j = k0; j < i; ++j)
                acc = pkfma(bc2(getel2(A2[i], j)), y2[j], acc);
            y2[i] = -acc;
        }

        v2f x2[NS];
        #pragma unroll
        for (int i = NS - 1; i >= 0; --i) {
            v2f acc = (i >= k0) ? y2[i] : (v2f){0.0f, 0.0f};
            #pragma unroll
            for (int c2 = i + 1; c2 < NS; ++c2)
                acc = pkfma(-bc2(getel2(A2[i], c2)), x2[c2], acc);
            x2[i] = acc * bc2(getel2(A2[i], i));
        }

        #pragma unroll
        for (int i = 0; i < NS; ++i) {
            tr = fmaf(x2[i].x, dk0[i], tr);
            tr = fmaf(x2[i].y, dk1[i], tr);
        }
    }

    det_out = det;
    tr_out  = tr;
}

// R10: persistent blocks. 128 threads (2 waves) per block; each block
// grid-strides over NBPB batches with double-buffered LDS staging:
//   prefetch(i+1 globals -> regs) | compute(i from buf[cur]) |
//   write regs -> buf[cur^1] | barrier.
// Rationale: R8 counters showed ~2.5 resident blocks/CU despite VGPR=60 /
// LDS=5KB (resource cap ~100%), and R9 (bigger blocks) didn't help ->
// short-lived blocks starve residency at the dispatcher. Long-lived blocks
// dispatch once and fill the machine; global latency hides under compute.
__global__ __launch_bounds__(128)
void kp_persist_kernel(const float* __restrict__ MO,
                       const float* __restrict__ d2MO,
                       const int*   __restrict__ cfg_up,
                       const int*   __restrict__ cfg_dn,
                       float*       __restrict__ out)
{
    __shared__ float smem[2][2][TSZ];        // [buf][MO^T / d2MO^T][32 x 20]

    const int u = threadIdx.x;               // 0..127
    const int r = u >> 3;                    // staging row 0..15
    const int c = (u & 7) * 4;               // staging col {0,4,...,28}

    // configs are batch-invariant: hoist out of the batch loop
    const int cidx = u >> 1;                 // config index 0..63
    const int s    = u & 1;                  // 0 = up, 1 = down
    const int* cfg = s ? cfg_dn : cfg_up;
    int4 cc0 = ((const int4*)cfg)[cidx * 2 + 0];
    int4 cc1 = ((const int4*)cfg)[cidx * 2 + 1];
    const int cols[NS] = {cc0.x, cc0.y, cc0.z, cc0.w, cc1.x, cc1.y, cc1.z, cc1.w};

    // prologue: stage batch blockIdx.x into buf 0
    int b = blockIdx.x;
    {
        const float* MOb = MO   + (size_t)b * NELEC * NMO;
        const float* d2b = d2MO + (size_t)b * NELEC * NMO;
        float4 v = *(const float4*)(MOb + r * NMO + c);
        float4 w = *(const float4*)(d2b + r * NMO + c);
        float* MOT = smem[0][0];
        float* D2T = smem[0][1];
        MOT[(c + 0) * TSTR + r] = v.x;  MOT[(c + 1) * TSTR + r] = v.y;
        MOT[(c + 2) * TSTR + r] = v.z;  MOT[(c + 3) * TSTR + r] = v.w;
        D2T[(c + 0) * TSTR + r] = w.x;  D2T[(c + 1) * TSTR + r] = w.y;
        D2T[(c + 2) * TSTR + r] = w.z;  D2T[(c + 3) * TSTR + r] = w.w;
    }
    __syncthreads();

    int cur = 0;
    #pragma unroll
    for (int it = 0; it < NBPB; ++it) {
        const bool more = (it + 1 < NBPB);

        // prefetch next batch's stage data into registers (loads fly during compute)
        float4 vn, wn;
        if (more) {
            const float* MOn = MO   + (size_t)(b + GRIDN) * NELEC * NMO;
            const float* d2n = d2MO + (size_t)(b + GRIDN) * NELEC * NMO;
            vn = *(const float4*)(MOn + r * NMO + c);
            wn = *(const float4*)(d2n + r * NMO + c);
        }

        // compute batch b from buf[cur]
        {
            float det, tr;
            solve8T(smem[cur][0], smem[cur][1], cols, s * NS, det, tr);
            float det_o = __shfl_xor(det, 1);
            float tr_o  = __shfl_xor(tr, 1);
            if (s == 0)
                out[(size_t)b * NCONF + cidx] = -0.5f * (tr + tr_o) * det * det_o;
        }

        if (more) {
            // write prefetched regs to the other buffer (no reader since the
            // barrier at the end of the previous iteration), then one barrier
            float* MOT = smem[cur ^ 1][0];
            float* D2T = smem[cur ^ 1][1];
            MOT[(c + 0) * TSTR + r] = vn.x;  MOT[(c + 1) * TSTR + r] = vn.y;
            MOT[(c + 2) * TSTR + r] = vn.z;  MOT[(c + 3) * TSTR + r] = vn.w;
            D2T[(c + 0) * TSTR + r] = wn.x;  D2T[(c + 1) * TSTR + r] = wn.y;
            D2T[(c + 2) * TSTR + r] = wn.z;  D2T[(c + 3) * TSTR + r] = wn.w;
            __syncthreads();
            cur ^= 1;
            b += GRIDN;
        }
    }
}

extern "C" void kernel_launch(void* const* d_in, const int* in_sizes, int n_in,
                              void* d_out, int out_size, void* d_ws, size_t ws_size,
                              hipStream_t stream)
{
    const float* MO     = (const float*)d_in[0];
    const float* d2MO   = (const float*)d_in[1];
    const int*   cfg_up = (const int*)d_in[2];
    const int*   cfg_dn = (const int*)d_in[3];
    float* out = (float*)d_out;

    dim3 grid(GRIDN);    // 2048 persistent-ish blocks, 4 batches each
    dim3 block(128);     // 2 waves: minimal barrier coupling
    kp_persist_kernel<<<grid, block, 0, stream>>>(MO, d2MO, cfg_up, cfg_dn, out);
}

// Round 12
// 89.327 us; speedup vs baseline: 1.1992x; 1.0409x over previous
//
#include <hip/hip_runtime.h>

#define NBATCH 8192
#define NELEC  16
#define NMO    32
#define NCONF  64
#define NS     8          // NUP == NDOWN == 8
#define TSTR   20         // A (fp32) row stride in floats (80 B: 16B-aligned for b128)
#define TSZ    (NMO * TSTR)
#define TSTRH  24         // D (fp16) row stride in HALVES (48 B: 16B-aligned for b128)
#define TSZH   (NMO * TSTRH)

typedef float    v2f   __attribute__((ext_vector_type(2)));
typedef _Float16 half8 __attribute__((ext_vector_type(8)));

__device__ __forceinline__ v2f pkfma(v2f a, v2f b, v2f c) {
#if __has_builtin(__builtin_elementwise_fma)
    return __builtin_elementwise_fma(a, b, c);
#else
    return a * b + c;
#endif
}
__device__ __forceinline__ v2f bc2(float s) { return (v2f){s, s}; }
__device__ __forceinline__ float getel2(const v2f (&R)[4], int j) {
    return (j & 1) ? R[j >> 1].y : R[j >> 1].x;
}
__device__ __forceinline__ void setel2(v2f (&R)[4], int j, float v) {
    if (j & 1) R[j >> 1].y = v; else R[j >> 1].x = v;
}

// R12: A stays fp32 in LDS (R11 PROVED fp16-A fails: input rounding of A is
// amplified by ||adj||·||dA·A^-1|| ~ 1/sigma_min -> absmax 4e8). D moves to
// fp16: D enters the output strictly LINEARLY (tr(adj(A)·D) — no kappa
// factor), so 4.9e-4 relative D-noise stays ~1-5e4 absolute, inside budget.
// DS effect: D-row = 16 B = ONE ds_read_b128 -> per-thread reads 32->24,
// DS bytes -25%, conflict cycles -25% on D reads (DS pipe is the modeled
// binder: ~16-19 us of the ~28 us kernel at 1.65x measured conflict factor).
// R3/R4 lesson: rows of D' pair with columns of A'^-1. R8 lesson: D' from
// global regresses (address-divergent loads choke TA; LDS banking wins).
__device__ __forceinline__ void solve8T(const float* __restrict__ MOT,
                                        const _Float16* __restrict__ D2T,
                                        const int (&cols)[NS], int eoff,
                                        float& det_out, float& tr_out)
{
    v2f A2[NS][4];                    // row j, pair p = cols {2p, 2p+1}
    #pragma unroll
    for (int j = 0; j < NS; ++j) {
        const float4* pa = (const float4*)(MOT + cols[j] * TSTR + eoff);
        float4 a0 = pa[0], a1 = pa[1];
        A2[j][0] = (v2f){a0.x, a0.y};
        A2[j][1] = (v2f){a0.z, a0.w};
        A2[j][2] = (v2f){a1.x, a1.y};
        A2[j][3] = (v2f){a1.z, a1.w};
    }

    // In-place LU, no pivot (packed over column pairs) — byte-identical to R7.
    float det = 1.0f;
    #pragma unroll
    for (int k = 0; k < NS; ++k) {
        float ukk = getel2(A2[k], k);
        det *= ukk;
        float pinv = __builtin_amdgcn_rcpf(ukk);
        #pragma unroll
        for (int r = k + 1; r < NS; ++r) {
            float m = getel2(A2[r], k) * pinv;
            v2f m2 = bc2(m);
            #pragma unroll
            for (int p = (k + 1) >> 1; p < 4; ++p)
                A2[r][p] = pkfma(-m2, A2[k][p], A2[r][p]);
            setel2(A2[r], k, m);
        }
        setel2(A2[k], k, pinv);
    }

    // tr = sum_k <x(k), row_k(D')> with A' x(k) = e_k; k pairs in lo/hi halves.
    float tr = 0.0f;
    #pragma unroll
    for (int t = 0; t < 4; ++t) {
        const int k0 = 2 * t, k1 = 2 * t + 1;

        // D' rows k0,k1: ONE b128 each (fp16), issued early to hide latency
        half8 hd0 = *(const half8*)(D2T + cols[k0] * TSTRH + eoff);
        half8 hd1 = *(const half8*)(D2T + cols[k1] * TSTRH + eoff);

        // forward: y2[i] = { y_{k0}[i], y_{k1}[i] }, y = L^-1 e_k
        v2f y2[NS];
        y2[k0] = (v2f){1.0f, 0.0f};
        y2[k1] = (v2f){-getel2(A2[k1], k0), 1.0f};
        #pragma unroll
        for (int i = k1 + 1; i < NS; ++i) {
            v2f acc = (v2f){0.0f, 0.0f};
            #pragma unroll
            for (int j = k0; j < i; ++j)
                acc = pkfma(bc2(getel2(A2[i], j)), y2[j], acc);
            y2[i] = -acc;
        }

        // back: U x = y
        v2f x2[NS];
        #pragma unroll
        for (int i = NS - 1; i >= 0; --i) {
            v2f acc = (i >= k0) ? y2[i] : (v2f){0.0f, 0.0f};
            #pragma unroll
            for (int c2 = i + 1; c2 < NS; ++c2)
                acc = pkfma(-bc2(getel2(A2[i], c2)), x2[c2], acc);
            x2[i] = acc * bc2(getel2(A2[i], i));
        }

        #pragma unroll
        for (int i = 0; i < NS; ++i) {
            tr = fmaf(x2[i].x, (float)hd0[i], tr);
            tr = fmaf(x2[i].y, (float)hd1[i], tr);
        }
    }

    det_out = det;
    tr_out  = tr;
}

// 2 threads per (batch, config) pair: lane parity = spin; combine via
// shfl_xor. Structure identical to R7 (best passing: 89.7 us bench).
__global__ __launch_bounds__(256)
void kp_dh_kernel(const float* __restrict__ MO,
                  const float* __restrict__ d2MO,
                  const int*   __restrict__ cfg_up,
                  const int*   __restrict__ cfg_dn,
                  float*       __restrict__ out)
{
    __shared__ float    smemA[2][TSZ];       // [batch-half][MO^T fp32, 32 x 20]
    __shared__ _Float16 smemD[2][TSZH];      // [batch-half][d2MO^T fp16, 32 x 24]

    const int tid  = threadIdx.x;
    const int half = tid >> 7;               // batch within block (0/1)
    const int u    = tid & 127;              // id within the batch's 128 threads
    const int b    = blockIdx.x * 2 + half;  // batch index

    float*    MOT = smemA[half];
    _Float16* D2T = smemD[half];

    const float* MOb = MO   + (size_t)b * NELEC * NMO;
    const float* d2b = d2MO + (size_t)b * NELEC * NMO;

    // Stage MO^T (fp32) and d2MO^T (fp16) with 128 threads: one float4 per
    // array per thread (coalesced global), transposed scatter into LDS.
    {
        int r = u >> 3;
        int c = (u & 7) * 4;
        float4 v = *(const float4*)(MOb + r * NMO + c);
        float4 w = *(const float4*)(d2b + r * NMO + c);
        MOT[(c + 0) * TSTR + r] = v.x;
        MOT[(c + 1) * TSTR + r] = v.y;
        MOT[(c + 2) * TSTR + r] = v.z;
        MOT[(c + 3) * TSTR + r] = v.w;
        D2T[(c + 0) * TSTRH + r] = (_Float16)w.x;
        D2T[(c + 1) * TSTRH + r] = (_Float16)w.y;
        D2T[(c + 2) * TSTRH + r] = (_Float16)w.z;
        D2T[(c + 3) * TSTRH + r] = (_Float16)w.w;
    }
    __syncthreads();

    const int cidx = u >> 1;                 // config index 0..63
    const int s    = u & 1;                  // 0 = up, 1 = down
    const int* cfg = s ? cfg_dn : cfg_up;
    int4 c0 = ((const int4*)cfg)[cidx * 2 + 0];
    int4 c1 = ((const int4*)cfg)[cidx * 2 + 1];
    const int cols[NS] = {c0.x, c0.y, c0.z, c0.w, c1.x, c1.y, c1.z, c1.w};

    float det, tr;
    solve8T(MOT, D2T, cols, s * NS, det, tr);

    // partner lane (u^1, same wave) holds the other spin channel
    float det_o = __shfl_xor(det, 1);
    float tr_o  = __shfl_xor(tr, 1);
    if (s == 0)
        out[(size_t)b * NCONF + cidx] = -0.5f * (tr + tr_o) * det * det_o;
}

extern "C" void kernel_launch(void* const* d_in, const int* in_sizes, int n_in,
                              void* d_out, int out_size, void* d_ws, size_t ws_size,
                              hipStream_t stream)
{
    const float* MO     = (const float*)d_in[0];
    const float* d2MO   = (const float*)d_in[1];
    const int*   cfg_up = (const int*)d_in[2];
    const int*   cfg_dn = (const int*)d_in[3];
    float* out = (float*)d_out;

    dim3 grid(NBATCH / 2);   // 4096 blocks, 2 batches per block, 2 threads per pair
    dim3 block(256);
    kp_dh_kernel<<<grid, block, 0, stream>>>(MO, d2MO, cfg_up, cfg_dn, out);
}